// Round 12
// baseline (1439.841 us; speedup 1.0000x reference)
//
#include <hip/hip_runtime.h>
#include <hip/hip_bf16.h>
#include <hip/hip_fp16.h>
#include <math.h>

#define NFEAT 512
#define H1 300
#define H2 200
#define NCLASS 40

typedef __attribute__((ext_vector_type(8))) _Float16 half8;
typedef __attribute__((ext_vector_type(4))) float f32x4;
typedef __attribute__((ext_vector_type(2))) unsigned int u32x2;

__device__ __forceinline__ void stage16(const void* gptr, void* ldsptr) {
    __builtin_amdgcn_global_load_lds(
        (const __attribute__((address_space(1))) unsigned int*)gptr,
        (__attribute__((address_space(3))) unsigned int*)ldsptr,
        16, 0, 0);
}

__device__ __forceinline__ unsigned short f2h(float f) {
    return __half_as_ushort(__float2half(f));
}
__device__ __forceinline__ float h2f(unsigned short u) {
    return __half2float(__ushort_as_half(u));
}
__device__ __forceinline__ float2 h2f2(unsigned int u) {
    __half2 h = *reinterpret_cast<__half2*>(&u);
    return __half22float2(h);
}
__device__ __forceinline__ unsigned pack2h(float a, float b) {
    return (unsigned)f2h(a) | ((unsigned)f2h(b) << 16);
}

// ---------------- CSR construction ----------------

__global__ __launch_bounds__(256) void count_dst_kernel(const int* __restrict__ dst,
                                                        int* __restrict__ counts, int E) {
    int i = blockIdx.x * blockDim.x + threadIdx.x;
    if (i < E) atomicAdd(&counts[dst[i]], 1);
}

// Two-level parallel scan.
#define SCAN_NB 256

__global__ __launch_bounds__(256) void scan_blocksum_kernel(const int* __restrict__ counts,
                                                            int* __restrict__ bsum, int N) {
    __shared__ int red[256];
    const int b = blockIdx.x, t = threadIdx.x;
    const int CHB = (N + SCAN_NB - 1) / SCAN_NB;
    const int lo = b * CHB, hi = min(lo + CHB, N);
    int s = 0;
    for (int i = lo + t; i < hi; i += 256) s += counts[i];
    red[t] = s;
    __syncthreads();
    #pragma unroll
    for (int off = 128; off; off >>= 1) {
        if (t < off) red[t] += red[t + off];
        __syncthreads();
    }
    if (t == 0) bsum[b] = red[0];
}

__global__ __launch_bounds__(256) void scan_boff_kernel(const int* __restrict__ bsum,
                                                        int* __restrict__ boff,
                                                        int* __restrict__ row_ptr, int N) {
    __shared__ int s[256];
    const int t = threadIdx.x;
    s[t] = bsum[t];
    __syncthreads();
    #pragma unroll
    for (int off = 1; off < 256; off <<= 1) {
        int v = (t >= off) ? s[t - off] : 0;
        __syncthreads();
        s[t] += v;
        __syncthreads();
    }
    boff[t] = (t > 0) ? s[t - 1] : 0;
    if (t == 255) row_ptr[N] = s[255];
}

__global__ __launch_bounds__(256) void scan_fill_kernel(const int* __restrict__ counts,
                                                        const int* __restrict__ boff,
                                                        int* __restrict__ row_ptr,
                                                        int* __restrict__ nextp, int N) {
    __shared__ int red[256];
    const int b = blockIdx.x, t = threadIdx.x;
    const int CHB = (N + SCAN_NB - 1) / SCAN_NB;
    const int lo = b * CHB, hi = min(lo + CHB, N);
    const int CHT = (CHB + 255) / 256;
    const int tl = min(lo + t * CHT, hi), th = min(tl + CHT, hi);
    int s = 0;
    for (int i = tl; i < th; i++) s += counts[i];
    red[t] = s;
    __syncthreads();
    #pragma unroll
    for (int off = 1; off < 256; off <<= 1) {
        int v = (t >= off) ? red[t - off] : 0;
        __syncthreads();
        red[t] += v;
        __syncthreads();
    }
    int run = boff[b] + ((t > 0) ? red[t - 1] : 0);
    for (int i = tl; i < th; i++) {
        row_ptr[i] = run;
        nextp[i] = run;
        run += counts[i];
    }
}

// Range-binned fill (R8-measured): pass p scatters only dst in [lo,hi); window L2-resident.

__global__ __launch_bounds__(256) void fill_csr_pass_kernel(const int* __restrict__ src,
                                                            const int* __restrict__ dst,
                                                            const float* __restrict__ ew,
                                                            int* __restrict__ next,
                                                            int2* __restrict__ csr_sw,
                                                            int E, int lo, int hi) {
    int i = blockIdx.x * blockDim.x + threadIdx.x;
    if (i < E) {
        int d = dst[i];
        if (d >= lo && d < hi) {
            int pos = atomicAdd(&next[d], 1);
            csr_sw[pos] = make_int2(src[i], __float_as_int(ew[i]));
        }
    }
}

// ---------------- X -> fp16 one-shot conversion ----------------

__global__ __launch_bounds__(256) void convert_x_kernel(const float* __restrict__ x,
                                                        unsigned short* __restrict__ X16,
                                                        int total8) {
    int stride = gridDim.x * 256;
    for (int i = blockIdx.x * 256 + threadIdx.x; i < total8; i += stride) {
        const float* p = x + (size_t)i * 8;
        float4 a = *(const float4*)p;
        float4 b = *(const float4*)(p + 4);
        half8 h;
        h[0] = (_Float16)a.x; h[1] = (_Float16)a.y;
        h[2] = (_Float16)a.z; h[3] = (_Float16)a.w;
        h[4] = (_Float16)b.x; h[5] = (_Float16)b.y;
        h[6] = (_Float16)b.z; h[7] = (_Float16)b.w;
        *(half8*)(X16 + (size_t)i * 8) = h;
    }
}

// ---------------- fused weight split: w [K][N] fp32 -> [NPAD][KPAD] fp16 hi/lo ----------------

__global__ __launch_bounds__(256) void split_weights_kernel(
        const float* __restrict__ w1, const float* __restrict__ w2, const float* __restrict__ w3,
        unsigned short* __restrict__ W1H, unsigned short* __restrict__ W1L,
        unsigned short* __restrict__ W2H, unsigned short* __restrict__ W2L,
        unsigned short* __restrict__ W3H, unsigned short* __restrict__ W3L) {
    int i = blockIdx.x * 256 + threadIdx.x;
    const float* w; unsigned short *H, *L; int K, N, KP;
    if (i < 163840) {                       // 320*512
        w = w1; H = W1H; L = W1L; K = 512; N = 300; KP = 512;
    } else if (i < 163840 + 81920) {        // 256*320
        i -= 163840; w = w2; H = W2H; L = W2L; K = 300; N = 200; KP = 320;
    } else {                                // 64*256
        i -= 245760; w = w3; H = W3H; L = W3L; K = 200; N = 40; KP = 256;
    }
    int n = i / KP, k = i - n * KP;
    float a = (n < N && k < K) ? w[(size_t)k * N + n] : 0.f;
    unsigned short h = f2h(a);
    H[i] = h;
    L[i] = f2h(a - h2f(h));
}

// ---------------- fp16 MFMA GEMM: B-only LDS, A direct global->VGPR ----------------
// NP may be < NT*64 (layer2 NP=200, layer3 NP=40): epilogue col-guarded.

template <int KPAD, int NT, bool AF32>
__global__ __launch_bounds__(256, 3) void gemm_f16_kernel(
        const void* __restrict__ A_,
        const unsigned short* __restrict__ Bhi, const unsigned short* __restrict__ Blo,
        unsigned short* __restrict__ C, int M, int NP, int MT) {
    __shared__ short Bs_hi[4096];
    __shared__ short Bs_lo[4096];

    const int id = blockIdx.x;
    const int g  = id / (8 * NT);
    const int r  = id % (8 * NT);
    const int nt = r >> 3;
    const int x  = r & 7;
    const int mt = g * 8 + x;
    if (mt >= MT) return;

    const int tid = threadIdx.x;
    const int wave = tid >> 6, lane = tid & 63;
    const int lm = lane & 15, quad = lane >> 4;
    const int bm = mt * 256, bn = nt * 64;

    f32x4 acc[4][4] = {};

    for (int k0 = 0; k0 < KPAD; k0 += 64) {
        #pragma unroll
        for (int i = 0; i < 2; i++) {
            int t = i * 256 + tid;
            int n = t >> 3;
            int c = (t & 7) ^ (n & 7);
            size_t goff = (size_t)(bn + n) * KPAD + (size_t)(k0 + c * 8);
            int lbase = (i * 256 + wave * 64) * 8;
            stage16(Bhi + goff, Bs_hi + lbase);
            stage16(Blo + goff, Bs_lo + lbase);
        }
        __syncthreads();

        #pragma unroll
        for (int h = 0; h < 2; h++) {
            const int cidx = h * 4 + quad;
            half8 a[4], bh[4], bl[4];
            #pragma unroll
            for (int i = 0; i < 4; i++) {
                int row = bm + wave * 64 + i * 16 + lm;
                row = row < M ? row : M - 1;
                size_t off = (size_t)row * KPAD + (size_t)(k0 + cidx * 8);
                if (AF32) {
                    const float* ap = (const float*)A_ + off;
                    float4 p = *(const float4*)ap;
                    float4 q = *(const float4*)(ap + 4);
                    half8 t8;
                    t8[0] = (_Float16)p.x; t8[1] = (_Float16)p.y;
                    t8[2] = (_Float16)p.z; t8[3] = (_Float16)p.w;
                    t8[4] = (_Float16)q.x; t8[5] = (_Float16)q.y;
                    t8[6] = (_Float16)q.z; t8[7] = (_Float16)q.w;
                    a[i] = t8;
                } else {
                    a[i] = *(const half8*)((const unsigned short*)A_ + off);
                }
            }
            #pragma unroll
            for (int j = 0; j < 4; j++) {
                int n = j * 16 + lm;
                int off = (n * 8 + (cidx ^ (n & 7))) * 8;
                bh[j] = *(const half8*)(Bs_hi + off);
                bl[j] = *(const half8*)(Bs_lo + off);
            }
            #pragma unroll
            for (int i = 0; i < 4; i++)
                #pragma unroll
                for (int j = 0; j < 4; j++) {
                    acc[i][j] = __builtin_amdgcn_mfma_f32_16x16x32_f16(a[i], bh[j], acc[i][j], 0, 0, 0);
                    acc[i][j] = __builtin_amdgcn_mfma_f32_16x16x32_f16(a[i], bl[j], acc[i][j], 0, 0, 0);
                }
        }
        __syncthreads();
    }

    #pragma unroll
    for (int i = 0; i < 4; i++) {
        #pragma unroll
        for (int j = 0; j < 4; j++) {
            #pragma unroll
            for (int r2 = 0; r2 < 4; r2++) {
                int row = bm + wave * 64 + i * 16 + quad * 4 + r2;
                int col = bn + j * 16 + lm;
                if (row < M && col < NP)
                    C[(size_t)row * NP + col] = f2h(acc[i][j][r2]);
            }
        }
    }
}

// ---------------- SpMM (CSR by dst), one wave per dst row, fp16 gather ----------------
// One uint4 (16B, 8 feats) load per edge per lane (R11-measured).

template <int F, int NPS, int NPO>
__global__ __launch_bounds__(256) void spmm_relu_f16_kernel(
        const int* __restrict__ row_ptr, const int2* __restrict__ csr_sw,
        const unsigned short* __restrict__ support, const float* __restrict__ bias,
        unsigned short* __restrict__ outp, int N) {
    constexpr int LPE = (F + 7) / 8;     // lanes per edge

    int row = blockIdx.x * 4 + (threadIdx.x >> 6);
    int lane = threadIdx.x & 63;
    if (row >= N) return;
    int beg = row_ptr[row], end = row_ptr[row + 1];
    const bool lact = lane < LPE;

    float acc[8] = {};

    int e = beg;
    int nb8 = (end - beg) >> 3;
    if (nb8 > 0) {
        int2 swbuf[8];
        #pragma unroll
        for (int q = 0; q < 8; q++) swbuf[q] = csr_sw[e + q];
        for (int b = 0; b < nb8; b++) {
            int s_[8]; float w_[8];
            #pragma unroll
            for (int q = 0; q < 8; q++) {
                s_[q] = __builtin_amdgcn_readfirstlane(swbuf[q].x);
                w_[q] = __uint_as_float((unsigned)__builtin_amdgcn_readfirstlane(swbuf[q].y));
            }
            uint4 u[8];
            if (lact) {
                #pragma unroll
                for (int q = 0; q < 8; q++)
                    u[q] = *(const uint4*)(support + (size_t)s_[q] * NPS + lane * 8);
            }
            int enext = e + 8;
            if (b + 1 < nb8) {
                #pragma unroll
                for (int q = 0; q < 8; q++) swbuf[q] = csr_sw[enext + q];
            }
            #pragma unroll
            for (int q = 0; q < 8; q++) {
                float2 a;
                a = h2f2(u[q].x); acc[0] += w_[q] * a.x; acc[1] += w_[q] * a.y;
                a = h2f2(u[q].y); acc[2] += w_[q] * a.x; acc[3] += w_[q] * a.y;
                a = h2f2(u[q].z); acc[4] += w_[q] * a.x; acc[5] += w_[q] * a.y;
                a = h2f2(u[q].w); acc[6] += w_[q] * a.x; acc[7] += w_[q] * a.y;
            }
            e = enext;
        }
    }
    for (; e + 3 < end; e += 4) {
        int s_[4]; float w_[4];
        #pragma unroll
        for (int q = 0; q < 4; q++) {
            int2 sw = csr_sw[e + q];
            s_[q] = __builtin_amdgcn_readfirstlane(sw.x);
            w_[q] = __uint_as_float((unsigned)__builtin_amdgcn_readfirstlane(sw.y));
        }
        uint4 u[4];
        if (lact) {
            #pragma unroll
            for (int q = 0; q < 4; q++)
                u[q] = *(const uint4*)(support + (size_t)s_[q] * NPS + lane * 8);
        }
        #pragma unroll
        for (int q = 0; q < 4; q++) {
            float2 a;
            a = h2f2(u[q].x); acc[0] += w_[q] * a.x; acc[1] += w_[q] * a.y;
            a = h2f2(u[q].y); acc[2] += w_[q] * a.x; acc[3] += w_[q] * a.y;
            a = h2f2(u[q].z); acc[4] += w_[q] * a.x; acc[5] += w_[q] * a.y;
            a = h2f2(u[q].w); acc[6] += w_[q] * a.x; acc[7] += w_[q] * a.y;
        }
    }
    for (; e < end; e++) {
        int2 sw = csr_sw[e];
        int ssrc = __builtin_amdgcn_readfirstlane(sw.x);
        float w0 = __uint_as_float((unsigned)__builtin_amdgcn_readfirstlane(sw.y));
        if (lact) {
            uint4 u = *(const uint4*)(support + (size_t)ssrc * NPS + lane * 8);
            float2 a;
            a = h2f2(u.x); acc[0] += w0 * a.x; acc[1] += w0 * a.y;
            a = h2f2(u.y); acc[2] += w0 * a.x; acc[3] += w0 * a.y;
            a = h2f2(u.z); acc[4] += w0 * a.x; acc[5] += w0 * a.y;
            a = h2f2(u.w); acc[6] += w0 * a.x; acc[7] += w0 * a.y;
        }
    }

    if (lane * 8 < NPO) {
        half8 o;
        #pragma unroll
        for (int k = 0; k < 8; k++) {
            int f = lane * 8 + k;
            float v = 0.f;
            if (f < F) v = fmaxf(acc[k] + bias[f], 0.f);
            o[k] = (_Float16)v;
        }
        *(half8*)(outp + (size_t)row * NPO + lane * 8) = o;
    }
}

// layer 3: aggregation (F=40, stride 40 fp16 packed) + bias + softmax fused.

__global__ __launch_bounds__(256) void spmm_softmax_kernel(
        const int* __restrict__ row_ptr, const int2* __restrict__ csr_sw,
        const unsigned short* __restrict__ support, const float* __restrict__ bias,
        float* __restrict__ out, int N) {
    int row = blockIdx.x * 4 + (threadIdx.x >> 6);
    int lane = threadIdx.x & 63;
    if (row >= N) return;
    int beg = row_ptr[row], end = row_ptr[row + 1];

    const int g = lane / 20;           // 0,1,2 active; 3 = idle lanes 60-63
    const int t = lane - g * 20;       // 0..19 (class dword index)
    const bool lact = lane < 60;

    float a0 = 0.f, a1 = 0.f;
    for (int e = beg; e < end; e += 3) {
        int ei = e + g;
        bool v = lact && (ei < end);
        int2 sw = csr_sw[v ? ei : beg];
        float w = v ? __int_as_float(sw.y) : 0.f;
        unsigned u = *(const unsigned*)(support + (size_t)sw.x * 40 + t * 2);
        float2 aa = h2f2(u);
        a0 += w * aa.x;
        a1 += w * aa.y;
    }
    a0 += __shfl(a0, lane + 20) + __shfl(a0, lane + 40);
    a1 += __shfl(a1, lane + 20) + __shfl(a1, lane + 40);

    const bool act = lane < 20;
    float v0 = 0.f, v1 = 0.f, m = -INFINITY;
    if (act) {
        float2 bb = ((const float2*)bias)[t];
        v0 = a0 + bb.x;
        v1 = a1 + bb.y;
        m = fmaxf(v0, v1);
    }
    #pragma unroll
    for (int off = 16; off; off >>= 1) m = fmaxf(m, __shfl_xor(m, off));
    float e0 = 0.f, e1 = 0.f;
    if (act) { e0 = expf(v0 - m); e1 = expf(v1 - m); }
    float s = e0 + e1;
    #pragma unroll
    for (int off = 16; off; off >>= 1) s += __shfl_xor(s, off);
    if (act) {
        float inv = 1.f / s;
        *(float2*)(out + (size_t)row * NCLASS + t * 2) = make_float2(e0 * inv, e1 * inv);
    }
}

// ---------------- launch ----------------

extern "C" void kernel_launch(void* const* d_in, const int* in_sizes, int n_in,
                              void* d_out, int out_size, void* d_ws, size_t ws_size,
                              hipStream_t stream) {
    const float* x   = (const float*)d_in[0];
    const int*   ei  = (const int*)d_in[1];
    const float* ew  = (const float*)d_in[2];
    const float* w1  = (const float*)d_in[3];
    const float* b1  = (const float*)d_in[4];
    const float* w2  = (const float*)d_in[5];
    const float* b2  = (const float*)d_in[6];
    const float* w3  = (const float*)d_in[7];
    const float* b3  = (const float*)d_in[8];
    float* out = (float*)d_out;

    const int N = in_sizes[0] / NFEAT;   // 100000
    const int E = in_sizes[2];           // 3200000
    const int* src = ei;
    const int* dst = ei + E;

    const int KP1 = 512, NP1 = 320, NT1 = 5;   // layer1: K=512 (X16 fp16), support 320-wide
    const int KP2 = 320, NP2 = 200, NT2 = 4;   // layer2: K=320, N=200, support 200-wide
    const int KP3 = 256, NP3 = 40,  NT3 = 1;   // layer3: K=256, N=40, support 40-wide

    char* base = (char*)d_ws;
    // Region A overlays (time-disjoint): X16 (102.4MB) -> H1H (64MB) -> H2H (51.2MB)
    unsigned short* X16 = (unsigned short*)(base);
    unsigned short* H1H = (unsigned short*)(base);
    unsigned short* H2H = (unsigned short*)(base);

    unsigned short* support = (unsigned short*)(base + 102400256);

    size_t wo = 102400256 + 64000256;
    auto walloc = [&](size_t bytes) { void* r = base + wo; wo += (bytes + 255) & ~(size_t)255; return r; };
    unsigned short* W1H = (unsigned short*)walloc((size_t)320 * 512 * 2);
    unsigned short* W1L = (unsigned short*)walloc((size_t)320 * 512 * 2);
    unsigned short* W2H = (unsigned short*)walloc((size_t)256 * 320 * 2);
    unsigned short* W2L = (unsigned short*)walloc((size_t)256 * 320 * 2);
    unsigned short* W3H = (unsigned short*)walloc((size_t)64 * 256 * 2);
    unsigned short* W3L = (unsigned short*)walloc((size_t)64 * 256 * 2);
    int*  counts  = (int*)walloc((size_t)N * 4);
    int*  row_ptr = (int*)walloc((size_t)(N + 1) * 4);
    int*  nextp   = (int*)walloc((size_t)N * 4);
    int*  bsum    = (int*)walloc(256 * 4);
    int*  boff    = (int*)walloc(256 * 4);
    int2* csr_sw  = (int2*)walloc((size_t)E * 8);

    const int MT = (N + 255) / 256;              // 391 M-tiles
    const int G  = (MT + 7) / 8;
    const int wgs = (N + 3) / 4;                 // 25000 blocks, 1 row/wave
    const int EB = (E + 255) / 256;

    // ---- CSR build: count + parallel scan + range-binned fill (8 passes) ----
    hipMemsetAsync(counts, 0, (size_t)N * 4, stream);
    count_dst_kernel<<<EB, 256, 0, stream>>>(dst, counts, E);
    scan_blocksum_kernel<<<SCAN_NB, 256, 0, stream>>>(counts, bsum, N);
    scan_boff_kernel<<<1, 256, 0, stream>>>(bsum, boff, row_ptr, N);
    scan_fill_kernel<<<SCAN_NB, 256, 0, stream>>>(counts, boff, row_ptr, nextp, N);
    {
        const int P = 8;
        const int CHN = (N + P - 1) / P;
        for (int p = 0; p < P; p++) {
            int lo = p * CHN;
            int hi = min(N, lo + CHN);
            fill_csr_pass_kernel<<<EB, 256, 0, stream>>>(src, dst, ew, nextp, csr_sw, E, lo, hi);
        }
    }

    // ---- weight conversion + X conversion ----
    split_weights_kernel<<<1024, 256, 0, stream>>>(w1, w2, w3, W1H, W1L, W2H, W2L, W3H, W3L);
    convert_x_kernel<<<2048, 256, 0, stream>>>(x, X16, N * NFEAT / 8);

    // ---- layer 1 (A = pre-converted fp16 X16) ----
    gemm_f16_kernel<KP1, NT1, false><<<G * 8 * NT1, 256, 0, stream>>>(
        X16, W1H, W1L, support, N, NP1, MT);
    spmm_relu_f16_kernel<H1, 320, 320><<<wgs, 256, 0, stream>>>(row_ptr, csr_sw, support, b1, H1H, N);

    // ---- layer 2 (support 200-wide; H2 out 256-wide zero-padded) ----
    gemm_f16_kernel<KP2, NT2, false><<<G * 8 * NT2, 256, 0, stream>>>(
        H1H, W2H, W2L, support, N, NP2, MT);
    spmm_relu_f16_kernel<H2, 200, 256><<<wgs, 256, 0, stream>>>(row_ptr, csr_sw, support, b2, H2H, N);

    // ---- layer 3 (support 40-wide packed) ----
    gemm_f16_kernel<KP3, NT3, false><<<G * 8 * NT3, 256, 0, stream>>>(
        H2H, W3H, W3L, support, N, NP3, MT);
    spmm_softmax_kernel<<<wgs, 256, 0, stream>>>(row_ptr, csr_sw, support, b3, out, N);
}

// Round 14
// 1408.295 us; speedup vs baseline: 1.0224x; 1.0224x over previous
//
#include <hip/hip_runtime.h>
#include <hip/hip_bf16.h>
#include <hip/hip_fp16.h>
#include <math.h>

#define NFEAT 512
#define H1 300
#define H2 200
#define NCLASS 40

typedef __attribute__((ext_vector_type(8))) _Float16 half8;
typedef __attribute__((ext_vector_type(4))) float f32x4;
typedef __attribute__((ext_vector_type(2))) unsigned int u32x2;

__device__ __forceinline__ void stage16(const void* gptr, void* ldsptr) {
    __builtin_amdgcn_global_load_lds(
        (const __attribute__((address_space(1))) unsigned int*)gptr,
        (__attribute__((address_space(3))) unsigned int*)ldsptr,
        16, 0, 0);
}

__device__ __forceinline__ unsigned short f2h(float f) {
    return __half_as_ushort(__float2half(f));
}
__device__ __forceinline__ float h2f(unsigned short u) {
    return __half2float(__ushort_as_half(u));
}
__device__ __forceinline__ float2 h2f2(unsigned int u) {
    __half2 h = *reinterpret_cast<__half2*>(&u);
    return __half22float2(h);
}
__device__ __forceinline__ unsigned pack2h(float a, float b) {
    return (unsigned)f2h(a) | ((unsigned)f2h(b) << 16);
}

// ---------------- CSR construction ----------------

__global__ __launch_bounds__(256) void count_dst_kernel(const int* __restrict__ dst,
                                                        int* __restrict__ counts, int E) {
    int i = blockIdx.x * blockDim.x + threadIdx.x;
    if (i < E) atomicAdd(&counts[dst[i]], 1);
}

// Two-level parallel scan.
#define SCAN_NB 256

__global__ __launch_bounds__(256) void scan_blocksum_kernel(const int* __restrict__ counts,
                                                            int* __restrict__ bsum, int N) {
    __shared__ int red[256];
    const int b = blockIdx.x, t = threadIdx.x;
    const int CHB = (N + SCAN_NB - 1) / SCAN_NB;
    const int lo = b * CHB, hi = min(lo + CHB, N);
    int s = 0;
    for (int i = lo + t; i < hi; i += 256) s += counts[i];
    red[t] = s;
    __syncthreads();
    #pragma unroll
    for (int off = 128; off; off >>= 1) {
        if (t < off) red[t] += red[t + off];
        __syncthreads();
    }
    if (t == 0) bsum[b] = red[0];
}

__global__ __launch_bounds__(256) void scan_boff_kernel(const int* __restrict__ bsum,
                                                        int* __restrict__ boff,
                                                        int* __restrict__ row_ptr, int N) {
    __shared__ int s[256];
    const int t = threadIdx.x;
    s[t] = bsum[t];
    __syncthreads();
    #pragma unroll
    for (int off = 1; off < 256; off <<= 1) {
        int v = (t >= off) ? s[t - off] : 0;
        __syncthreads();
        s[t] += v;
        __syncthreads();
    }
    boff[t] = (t > 0) ? s[t - 1] : 0;
    if (t == 255) row_ptr[N] = s[255];
}

__global__ __launch_bounds__(256) void scan_fill_kernel(const int* __restrict__ counts,
                                                        const int* __restrict__ boff,
                                                        int* __restrict__ row_ptr,
                                                        int* __restrict__ nextp, int N) {
    __shared__ int red[256];
    const int b = blockIdx.x, t = threadIdx.x;
    const int CHB = (N + SCAN_NB - 1) / SCAN_NB;
    const int lo = b * CHB, hi = min(lo + CHB, N);
    const int CHT = (CHB + 255) / 256;
    const int tl = min(lo + t * CHT, hi), th = min(tl + CHT, hi);
    int s = 0;
    for (int i = tl; i < th; i++) s += counts[i];
    red[t] = s;
    __syncthreads();
    #pragma unroll
    for (int off = 1; off < 256; off <<= 1) {
        int v = (t >= off) ? red[t - off] : 0;
        __syncthreads();
        red[t] += v;
        __syncthreads();
    }
    int run = boff[b] + ((t > 0) ? red[t - 1] : 0);
    for (int i = tl; i < th; i++) {
        row_ptr[i] = run;
        nextp[i] = run;
        run += counts[i];
    }
}

// Range-binned fill: pass p scatters only dst in [lo,hi). 4 passes -> 6.4MB window
// (still L2-resident) with half the re-read traffic of 8 passes.

__global__ __launch_bounds__(256) void fill_csr_pass_kernel(const int* __restrict__ src,
                                                            const int* __restrict__ dst,
                                                            const float* __restrict__ ew,
                                                            int* __restrict__ next,
                                                            int2* __restrict__ csr_sw,
                                                            int E, int lo, int hi) {
    int i = blockIdx.x * blockDim.x + threadIdx.x;
    if (i < E) {
        int d = dst[i];
        if (d >= lo && d < hi) {
            int pos = atomicAdd(&next[d], 1);
            csr_sw[pos] = make_int2(src[i], __float_as_int(ew[i]));
        }
    }
}

// ---------------- fused weight split: w [K][N] fp32 -> [NPAD][KPAD] fp16 hi/lo ----------------

__global__ __launch_bounds__(256) void split_weights_kernel(
        const float* __restrict__ w1, const float* __restrict__ w2, const float* __restrict__ w3,
        unsigned short* __restrict__ W1H, unsigned short* __restrict__ W1L,
        unsigned short* __restrict__ W2H, unsigned short* __restrict__ W2L,
        unsigned short* __restrict__ W3H, unsigned short* __restrict__ W3L) {
    int i = blockIdx.x * 256 + threadIdx.x;
    const float* w; unsigned short *H, *L; int K, N, KP;
    if (i < 163840) {                       // 320*512
        w = w1; H = W1H; L = W1L; K = 512; N = 300; KP = 512;
    } else if (i < 163840 + 81920) {        // 256*320
        i -= 163840; w = w2; H = W2H; L = W2L; K = 300; N = 200; KP = 320;
    } else {                                // 64*256
        i -= 245760; w = w3; H = W3H; L = W3L; K = 200; N = 40; KP = 256;
    }
    int n = i / KP, k = i - n * KP;
    float a = (n < N && k < K) ? w[(size_t)k * N + n] : 0.f;
    unsigned short h = f2h(a);
    H[i] = h;
    L[i] = f2h(a - h2f(h));
}

// ---------------- fp16 MFMA GEMM: B-only LDS, A direct global->VGPR ----------------
// NP may be < NT*64 (layer2 NP=200, layer3 NP=40): epilogue col-guarded.
// AF32: A read as fp32 with in-register cvt (layer 1 reads X directly; measured
// equal to the X16-precompute path -> keep AF32, no convert pass).

template <int KPAD, int NT, bool AF32>
__global__ __launch_bounds__(256, 3) void gemm_f16_kernel(
        const void* __restrict__ A_,
        const unsigned short* __restrict__ Bhi, const unsigned short* __restrict__ Blo,
        unsigned short* __restrict__ C, int M, int NP, int MT) {
    __shared__ short Bs_hi[4096];
    __shared__ short Bs_lo[4096];

    const int id = blockIdx.x;
    const int g  = id / (8 * NT);
    const int r  = id % (8 * NT);
    const int nt = r >> 3;
    const int x  = r & 7;
    const int mt = g * 8 + x;
    if (mt >= MT) return;

    const int tid = threadIdx.x;
    const int wave = tid >> 6, lane = tid & 63;
    const int lm = lane & 15, quad = lane >> 4;
    const int bm = mt * 256, bn = nt * 64;

    f32x4 acc[4][4] = {};

    for (int k0 = 0; k0 < KPAD; k0 += 64) {
        #pragma unroll
        for (int i = 0; i < 2; i++) {
            int t = i * 256 + tid;
            int n = t >> 3;
            int c = (t & 7) ^ (n & 7);
            size_t goff = (size_t)(bn + n) * KPAD + (size_t)(k0 + c * 8);
            int lbase = (i * 256 + wave * 64) * 8;
            stage16(Bhi + goff, Bs_hi + lbase);
            stage16(Blo + goff, Bs_lo + lbase);
        }
        __syncthreads();

        #pragma unroll
        for (int h = 0; h < 2; h++) {
            const int cidx = h * 4 + quad;
            half8 a[4], bh[4], bl[4];
            #pragma unroll
            for (int i = 0; i < 4; i++) {
                int row = bm + wave * 64 + i * 16 + lm;
                row = row < M ? row : M - 1;
                size_t off = (size_t)row * KPAD + (size_t)(k0 + cidx * 8);
                if (AF32) {
                    const float* ap = (const float*)A_ + off;
                    float4 p = *(const float4*)ap;
                    float4 q = *(const float4*)(ap + 4);
                    half8 t8;
                    t8[0] = (_Float16)p.x; t8[1] = (_Float16)p.y;
                    t8[2] = (_Float16)p.z; t8[3] = (_Float16)p.w;
                    t8[4] = (_Float16)q.x; t8[5] = (_Float16)q.y;
                    t8[6] = (_Float16)q.z; t8[7] = (_Float16)q.w;
                    a[i] = t8;
                } else {
                    a[i] = *(const half8*)((const unsigned short*)A_ + off);
                }
            }
            #pragma unroll
            for (int j = 0; j < 4; j++) {
                int n = j * 16 + lm;
                int off = (n * 8 + (cidx ^ (n & 7))) * 8;
                bh[j] = *(const half8*)(Bs_hi + off);
                bl[j] = *(const half8*)(Bs_lo + off);
            }
            #pragma unroll
            for (int i = 0; i < 4; i++)
                #pragma unroll
                for (int j = 0; j < 4; j++) {
                    acc[i][j] = __builtin_amdgcn_mfma_f32_16x16x32_f16(a[i], bh[j], acc[i][j], 0, 0, 0);
                    acc[i][j] = __builtin_amdgcn_mfma_f32_16x16x32_f16(a[i], bl[j], acc[i][j], 0, 0, 0);
                }
        }
        __syncthreads();
    }

    #pragma unroll
    for (int i = 0; i < 4; i++) {
        #pragma unroll
        for (int j = 0; j < 4; j++) {
            #pragma unroll
            for (int r2 = 0; r2 < 4; r2++) {
                int row = bm + wave * 64 + i * 16 + quad * 4 + r2;
                int col = bn + j * 16 + lm;
                if (row < M && col < NP)
                    C[(size_t)row * NP + col] = f2h(acc[i][j][r2]);
            }
        }
    }
}

// ---------------- SpMM (CSR by dst), one wave per dst row, fp16 gather ----------------
// One uint4 (16B, 8 feats) load per edge per lane (R11-measured).

template <int F, int NPS, int NPO>
__global__ __launch_bounds__(256) void spmm_relu_f16_kernel(
        const int* __restrict__ row_ptr, const int2* __restrict__ csr_sw,
        const unsigned short* __restrict__ support, const float* __restrict__ bias,
        unsigned short* __restrict__ outp, int N) {
    constexpr int LPE = (F + 7) / 8;     // lanes per edge

    int row = blockIdx.x * 4 + (threadIdx.x >> 6);
    int lane = threadIdx.x & 63;
    if (row >= N) return;
    int beg = row_ptr[row], end = row_ptr[row + 1];
    const bool lact = lane < LPE;

    float acc[8] = {};

    int e = beg;
    int nb8 = (end - beg) >> 3;
    if (nb8 > 0) {
        int2 swbuf[8];
        #pragma unroll
        for (int q = 0; q < 8; q++) swbuf[q] = csr_sw[e + q];
        for (int b = 0; b < nb8; b++) {
            int s_[8]; float w_[8];
            #pragma unroll
            for (int q = 0; q < 8; q++) {
                s_[q] = __builtin_amdgcn_readfirstlane(swbuf[q].x);
                w_[q] = __uint_as_float((unsigned)__builtin_amdgcn_readfirstlane(swbuf[q].y));
            }
            uint4 u[8];
            if (lact) {
                #pragma unroll
                for (int q = 0; q < 8; q++)
                    u[q] = *(const uint4*)(support + (size_t)s_[q] * NPS + lane * 8);
            }
            int enext = e + 8;
            if (b + 1 < nb8) {
                #pragma unroll
                for (int q = 0; q < 8; q++) swbuf[q] = csr_sw[enext + q];
            }
            #pragma unroll
            for (int q = 0; q < 8; q++) {
                float2 a;
                a = h2f2(u[q].x); acc[0] += w_[q] * a.x; acc[1] += w_[q] * a.y;
                a = h2f2(u[q].y); acc[2] += w_[q] * a.x; acc[3] += w_[q] * a.y;
                a = h2f2(u[q].z); acc[4] += w_[q] * a.x; acc[5] += w_[q] * a.y;
                a = h2f2(u[q].w); acc[6] += w_[q] * a.x; acc[7] += w_[q] * a.y;
            }
            e = enext;
        }
    }
    for (; e + 3 < end; e += 4) {
        int s_[4]; float w_[4];
        #pragma unroll
        for (int q = 0; q < 4; q++) {
            int2 sw = csr_sw[e + q];
            s_[q] = __builtin_amdgcn_readfirstlane(sw.x);
            w_[q] = __uint_as_float((unsigned)__builtin_amdgcn_readfirstlane(sw.y));
        }
        uint4 u[4];
        if (lact) {
            #pragma unroll
            for (int q = 0; q < 4; q++)
                u[q] = *(const uint4*)(support + (size_t)s_[q] * NPS + lane * 8);
        }
        #pragma unroll
        for (int q = 0; q < 4; q++) {
            float2 a;
            a = h2f2(u[q].x); acc[0] += w_[q] * a.x; acc[1] += w_[q] * a.y;
            a = h2f2(u[q].y); acc[2] += w_[q] * a.x; acc[3] += w_[q] * a.y;
            a = h2f2(u[q].z); acc[4] += w_[q] * a.x; acc[5] += w_[q] * a.y;
            a = h2f2(u[q].w); acc[6] += w_[q] * a.x; acc[7] += w_[q] * a.y;
        }
    }
    for (; e < end; e++) {
        int2 sw = csr_sw[e];
        int ssrc = __builtin_amdgcn_readfirstlane(sw.x);
        float w0 = __uint_as_float((unsigned)__builtin_amdgcn_readfirstlane(sw.y));
        if (lact) {
            uint4 u = *(const uint4*)(support + (size_t)ssrc * NPS + lane * 8);
            float2 a;
            a = h2f2(u.x); acc[0] += w0 * a.x; acc[1] += w0 * a.y;
            a = h2f2(u.y); acc[2] += w0 * a.x; acc[3] += w0 * a.y;
            a = h2f2(u.z); acc[4] += w0 * a.x; acc[5] += w0 * a.y;
            a = h2f2(u.w); acc[6] += w0 * a.x; acc[7] += w0 * a.y;
        }
    }

    if (lane * 8 < NPO) {
        half8 o;
        #pragma unroll
        for (int k = 0; k < 8; k++) {
            int f = lane * 8 + k;
            float v = 0.f;
            if (f < F) v = fmaxf(acc[k] + bias[f], 0.f);
            o[k] = (_Float16)v;
        }
        *(half8*)(outp + (size_t)row * NPO + lane * 8) = o;
    }
}

// layer 3: aggregation (F=40, stride 40 fp16 packed) + bias + softmax fused.

__global__ __launch_bounds__(256) void spmm_softmax_kernel(
        const int* __restrict__ row_ptr, const int2* __restrict__ csr_sw,
        const unsigned short* __restrict__ support, const float* __restrict__ bias,
        float* __restrict__ out, int N) {
    int row = blockIdx.x * 4 + (threadIdx.x >> 6);
    int lane = threadIdx.x & 63;
    if (row >= N) return;
    int beg = row_ptr[row], end = row_ptr[row + 1];

    const int g = lane / 20;           // 0,1,2 active; 3 = idle lanes 60-63
    const int t = lane - g * 20;       // 0..19 (class dword index)
    const bool lact = lane < 60;

    float a0 = 0.f, a1 = 0.f;
    for (int e = beg; e < end; e += 3) {
        int ei = e + g;
        bool v = lact && (ei < end);
        int2 sw = csr_sw[v ? ei : beg];
        float w = v ? __int_as_float(sw.y) : 0.f;
        unsigned u = *(const unsigned*)(support + (size_t)sw.x * 40 + t * 2);
        float2 aa = h2f2(u);
        a0 += w * aa.x;
        a1 += w * aa.y;
    }
    a0 += __shfl(a0, lane + 20) + __shfl(a0, lane + 40);
    a1 += __shfl(a1, lane + 20) + __shfl(a1, lane + 40);

    const bool act = lane < 20;
    float v0 = 0.f, v1 = 0.f, m = -INFINITY;
    if (act) {
        float2 bb = ((const float2*)bias)[t];
        v0 = a0 + bb.x;
        v1 = a1 + bb.y;
        m = fmaxf(v0, v1);
    }
    #pragma unroll
    for (int off = 16; off; off >>= 1) m = fmaxf(m, __shfl_xor(m, off));
    float e0 = 0.f, e1 = 0.f;
    if (act) { e0 = expf(v0 - m); e1 = expf(v1 - m); }
    float s = e0 + e1;
    #pragma unroll
    for (int off = 16; off; off >>= 1) s += __shfl_xor(s, off);
    if (act) {
        float inv = 1.f / s;
        *(float2*)(out + (size_t)row * NCLASS + t * 2) = make_float2(e0 * inv, e1 * inv);
    }
}

// ---------------- launch ----------------

extern "C" void kernel_launch(void* const* d_in, const int* in_sizes, int n_in,
                              void* d_out, int out_size, void* d_ws, size_t ws_size,
                              hipStream_t stream) {
    const float* x   = (const float*)d_in[0];
    const int*   ei  = (const int*)d_in[1];
    const float* ew  = (const float*)d_in[2];
    const float* w1  = (const float*)d_in[3];
    const float* b1  = (const float*)d_in[4];
    const float* w2  = (const float*)d_in[5];
    const float* b2  = (const float*)d_in[6];
    const float* w3  = (const float*)d_in[7];
    const float* b3  = (const float*)d_in[8];
    float* out = (float*)d_out;

    const int N = in_sizes[0] / NFEAT;   // 100000
    const int E = in_sizes[2];           // 3200000
    const int* src = ei;
    const int* dst = ei + E;

    const int KP1 = 512, NP1 = 320, NT1 = 5;   // layer1: K=512 (fp32 X direct), support 320-wide
    const int KP2 = 320, NP2 = 200, NT2 = 4;   // layer2: K=320, N=200, support 200-wide
    const int KP3 = 256, NP3 = 40,  NT3 = 1;   // layer3: K=256, N=40, support 40-wide

    char* base = (char*)d_ws;
    // Region A overlays (time-disjoint): H1H (64MB) -> H2H (51.2MB)
    unsigned short* H1H = (unsigned short*)(base);
    unsigned short* H2H = (unsigned short*)(base);

    unsigned short* support = (unsigned short*)(base + 102400256);

    size_t wo = 102400256 + 64000256;
    auto walloc = [&](size_t bytes) { void* r = base + wo; wo += (bytes + 255) & ~(size_t)255; return r; };
    unsigned short* W1H = (unsigned short*)walloc((size_t)320 * 512 * 2);
    unsigned short* W1L = (unsigned short*)walloc((size_t)320 * 512 * 2);
    unsigned short* W2H = (unsigned short*)walloc((size_t)256 * 320 * 2);
    unsigned short* W2L = (unsigned short*)walloc((size_t)256 * 320 * 2);
    unsigned short* W3H = (unsigned short*)walloc((size_t)64 * 256 * 2);
    unsigned short* W3L = (unsigned short*)walloc((size_t)64 * 256 * 2);
    int*  counts  = (int*)walloc((size_t)N * 4);
    int*  row_ptr = (int*)walloc((size_t)(N + 1) * 4);
    int*  nextp   = (int*)walloc((size_t)N * 4);
    int*  bsum    = (int*)walloc(256 * 4);
    int*  boff    = (int*)walloc(256 * 4);
    int2* csr_sw  = (int2*)walloc((size_t)E * 8);

    const int MT = (N + 255) / 256;              // 391 M-tiles
    const int G  = (MT + 7) / 8;
    const int wgs = (N + 3) / 4;                 // 25000 blocks, 1 row/wave
    const int EB = (E + 255) / 256;

    // ---- CSR build: count + parallel scan + range-binned fill (4 passes) ----
    hipMemsetAsync(counts, 0, (size_t)N * 4, stream);
    count_dst_kernel<<<EB, 256, 0, stream>>>(dst, counts, E);
    scan_blocksum_kernel<<<SCAN_NB, 256, 0, stream>>>(counts, bsum, N);
    scan_boff_kernel<<<1, 256, 0, stream>>>(bsum, boff, row_ptr, N);
    scan_fill_kernel<<<SCAN_NB, 256, 0, stream>>>(counts, boff, row_ptr, nextp, N);
    {
        const int P = 4;
        const int CHN = (N + P - 1) / P;
        for (int p = 0; p < P; p++) {
            int lo = p * CHN;
            int hi = min(N, lo + CHN);
            fill_csr_pass_kernel<<<EB, 256, 0, stream>>>(src, dst, ew, nextp, csr_sw, E, lo, hi);
        }
    }

    // ---- weight conversion ----
    split_weights_kernel<<<1024, 256, 0, stream>>>(w1, w2, w3, W1H, W1L, W2H, W2L, W3H, W3L);

    // ---- layer 1 (A = fp32 X, in-register cvt; R11-measured best) ----
    gemm_f16_kernel<KP1, NT1, true><<<G * 8 * NT1, 256, 0, stream>>>(
        x, W1H, W1L, support, N, NP1, MT);
    spmm_relu_f16_kernel<H1, 320, 320><<<wgs, 256, 0, stream>>>(row_ptr, csr_sw, support, b1, H1H, N);

    // ---- layer 2 (support 200-wide; H2 out 256-wide zero-padded) ----
    gemm_f16_kernel<KP2, NT2, false><<<G * 8 * NT2, 256, 0, stream>>>(
        H1H, W2H, W2L, support, N, NP2, MT);
    spmm_relu_f16_kernel<H2, 200, 256><<<wgs, 256, 0, stream>>>(row_ptr, csr_sw, support, b2, H2H, N);

    // ---- layer 3 (support 40-wide packed) ----
    gemm_f16_kernel<KP3, NT3, false><<<G * 8 * NT3, 256, 0, stream>>>(
        H2H, W3H, W3L, support, N, NP3, MT);
    spmm_softmax_kernel<<<wgs, 256, 0, stream>>>(row_ptr, csr_sw, support, b3, out, N);
}